// Round 4
// baseline (96.055 us; speedup 1.0000x reference)
//
#include <hip/hip_runtime.h>

// B=2, Hi=Wi=64, Di=32, C=16, F=8, strides (2,2,2), k=3x3x3, Ho=Wo=128, Do=64.
constexpr int Bc  = 2;
constexpr int HiC = 64, WiC = 64, DiC = 32;
constexpr int Cc  = 16, Fc  = 8;
constexpr int HoC = 128, WoC = 128, DoC = 64;

constexpr int SLAB_SHORTS = DiC * Cc;                  // 512 shorts = 1 KiB slab
constexpr int NSLAB       = 18;                        // 2 hi rows x 9 wi cols
constexpr int ZOFF        = NSLAB * SLAB_SHORTS * 2;   // LDS byte offset of zero block

typedef __attribute__((ext_vector_type(8))) short short8;   // 8 bf16 = A/B frag
typedef __attribute__((ext_vector_type(4))) float f32x4;    // MFMA accumulator

__device__ alignas(16) const float FZERO[8] = {0, 0, 0, 0, 0, 0, 0, 0};

__device__ __forceinline__ unsigned pk2(float x, float y) {   // RNE f32x2 -> bf16x2
    unsigned ux = __float_as_uint(x), uy = __float_as_uint(y);
    ux += ((ux >> 16) & 1u) + 0x7FFFu;
    uy += ((uy >> 16) & 1u) + 0x7FFFu;
    return (ux >> 16) | (uy & 0xFFFF0000u);
}
__device__ __forceinline__ short8 pack8(float4 a, float4 b) {
    union { unsigned u[4]; short8 s; } r;
    r.u[0] = pk2(a.x, a.y); r.u[1] = pk2(a.z, a.w);
    r.u[2] = pk2(b.x, b.y); r.u[3] = pk2(b.z, b.w);
    return r.s;
}

// Wave = 4 same-parity columns of one output row. Per column: out[do,f] over
// (pos,kd,c) packed in MFMA K=32. E rows (bp+do+1 even): per position, k-halves
// = kd0/kd2. O rows (kd=1): two positions per MFMA.
// Round 12 (SWAPPED OPERANDS): mfma(W, X, acc) — A and B fragment layouts are
// structurally identical (lane&15 = non-K index, quad*8+j = K), so the same
// fragment code serves both roles. D is now [f][do-idx]: row = f = quad*4+reg
// (quads 0,1 valid), col = do-index = lane&15. Each acc f32x4 = 4 consecutive
// f of one output row -> direct global_store_dwordx4, NO LDS transpose, no
// wave barriers. hidx mapping unchanged: kh==0 -> row r+1, kh 1/2 -> row r.
template<int CLS>
__device__ __forceinline__ void doCols(const short* __restrict__ slabs,
                                       const int*   __restrict__ bp,
                                       const float* __restrict__ kern,
                                       float*       __restrict__ out,
                                       int b, int ho, int wo0, int wi0, int lane) {
    constexpr int NP = (CLS == 0) ? 1 : ((CLS == 3) ? 4 : 2);
    constexpr int OP = (NP + 1) / 2;
    constexpr int KH[4][4] = {{1,0,0,0},{1,1,0,0},{0,2,0,0},{0,0,2,2}};
    constexpr int KW[4][4] = {{1,0,0,0},{0,2,0,0},{1,1,0,0},{0,2,0,2}};

    const int quad = lane >> 4, n = lane & 15;
    const int half = quad >> 1, chalf = quad & 1;   // k-half, channel-half
    const int chalfB = chalf * 16;                  // byte offset within di row

    // ---- W fragments in-register from f32 kern (amortized over 4 columns).
    // As A-operand: A[m=lane&15][k=quad*8+j] = w[f=m][k]; rows m>=Fc zeroed. ----
    short8 bE[NP], bO[OP];
    #pragma unroll
    for (int p = 0; p < NP; ++p) {
        const int kp = KH[CLS][p] * 3 + KW[CLS][p];
        const float* wp = (n < Fc)
            ? kern + (kp * 3 + 2 * half) * 128 + n * 16 + chalf * 8 : FZERO;
        bE[p] = pack8(*(const float4*)wp, *(const float4*)(wp + 4));
    }
    #pragma unroll
    for (int pp = 0; pp < OP; ++pp) {
        const int  PA   = (2 * pp < NP) ? 2 * pp : 0;
        const bool hasB = (2 * pp + 1) < NP;
        const int  PB   = hasB ? (2 * pp + 1) : 0;
        const int kpa = KH[CLS][PA] * 3 + KW[CLS][PA];
        const int kpb = KH[CLS][PB] * 3 + KW[CLS][PB];
        const int kp  = half ? kpb : kpa;
        const bool v  = (n < Fc) && (!half || hasB);
        const float* wp = v ? kern + (kp * 3 + 1) * 128 + n * 16 + chalf * 8 : FZERO;
        bO[pp] = pack8(*(const float4*)wp, *(const float4*)(wp + 4));
    }

    // ---- phase 1: ALL scalar loads for all 4 columns ----
    int colx[4], bpcol[4], bpgr[4][NP], pxo[4][NP]; bool pvs[4][NP];
    #pragma unroll
    for (int cc = 0; cc < 4; ++cc) {
        const int wo = wo0 + 2 * cc;
        colx[cc]  = __builtin_amdgcn_readfirstlane((b * HoC + ho) * WoC + wo);
        bpcol[cc] = bp[colx[cc]];                    // uniform -> s_load
        #pragma unroll
        for (int p = 0; p < NP; ++p) {
            const int kh = KH[CLS][p], kw = KW[CLS][p];
            int hi = (ho + 1 - kh) >> 1; hi = hi > HiC - 1 ? HiC - 1 : hi;
            int wi = (wo + 1 - kw) >> 1; wi = wi > WiC - 1 ? WiC - 1 : wi;
            pvs[cc][p] = (kh != 0 || ho + 1 < HoC) && (kw != 0 || wo + 1 < WoC);
            const int sidx =
                __builtin_amdgcn_readfirstlane((b * HoC + 2 * hi) * WoC + 2 * wi);
            bpgr[cc][p] = bp[sidx];                  // uniform -> s_load
            const int hidx = (kh == 0) ? 1 : 0;      // row r+1 = kh0, row r = kh1/2
            pxo[cc][p] = __builtin_amdgcn_readfirstlane(
                             (hidx * 9 + (wi - wi0)) << 10);   // LDS bytes
        }
    }

    // ---- phase 2: per column taps + MFMA + direct-store epilogue ----
    #pragma unroll
    for (int cc = 0; cc < 4; ++cc) {
        const int bp_col = bpcol[cc];
        const int q      = (bp_col + 1) & 1;
        const int baseE  = (bp_col + q + 1) >> 1;    // di(kd0) = baseE+n-bpg
        const int baseO  = (bp_col + 1 - q) >> 1;    // di(kd1) = baseO+n-bpg
        int sE[NP], sO[NP];
        #pragma unroll
        for (int p = 0; p < NP; ++p) {               // sentinel folds validity
            const int bpg = bpgr[cc][p] >> 1;
            sE[p] = pvs[cc][p] ? baseE - bpg : -100000;
            sO[p] = pvs[cc][p] ? baseO - bpg : -100000;
        }

        f32x4 accE[2] = {{0.f,0.f,0.f,0.f},{0.f,0.f,0.f,0.f}};
        f32x4 accO[2] = {{0.f,0.f,0.f,0.f},{0.f,0.f,0.f,0.f}};

        #pragma unroll
        for (int g = 0; g < 2; ++g) {
            #pragma unroll
            for (int p = 0; p < NP; ++p) {           // E: kd = 2*half
                const int  di = sE[p] + 16 * g + n - half;
                const bool ok = (unsigned)di < (unsigned)DiC;
                const int  off = ok ? pxo[cc][p] + di * 32 + chalfB : ZOFF;
                short8 a = *(const short8*)((const char*)slabs + off);   // ds_read_b128
                accE[g] = __builtin_amdgcn_mfma_f32_16x16x32_bf16(bE[p], a, accE[g], 0, 0, 0);
            }
            #pragma unroll
            for (int pp = 0; pp < OP; ++pp) {        // O: k-halves = two positions
                const int  PA   = (2 * pp < NP) ? 2 * pp : 0;
                const bool hasB = (2 * pp + 1) < NP;
                const int  PB   = hasB ? (2 * pp + 1) : 0;
                const int  sOs  = half ? (hasB ? sO[PB] : -100000) : sO[PA];
                const int  pxs  = half ? pxo[cc][PB] : pxo[cc][PA];
                const int  di = sOs + 16 * g + n;
                const bool ok = (unsigned)di < (unsigned)DiC;
                const int  off = ok ? pxs + di * 32 + chalfB : ZOFF;
                short8 a = *(const short8*)((const char*)slabs + off);   // ds_read_b128
                accO[g] = __builtin_amdgcn_mfma_f32_16x16x32_bf16(bO[pp], a, accO[g], 0, 0, 0);
            }
        }

        // Direct epilogue: lane (quad<2, n) holds f = quad*4..+3 for do-index
        // m2 = 16g+n. do_E = 2*m2+q, do_O = 2*m2+1-q. 16B stores, fully covering
        // the 2 KiB column (E+O interleave rows).
        if (quad < 2) {
            float* outc = out + (size_t)colx[cc] * (DoC * Fc) + quad * 4;
            #pragma unroll
            for (int g = 0; g < 2; ++g) {
                const int m2 = 16 * g + n;
                *(float4*)(outc + (2 * m2 + q)     * Fc) = *(const float4*)&accE[g];
                *(float4*)(outc + (2 * m2 + 1 - q) * Fc) = *(const float4*)&accO[g];
            }
        }
    }
}

__global__ __launch_bounds__(256, 3)
void sconv_mfma(const float* __restrict__ img, const int* __restrict__ bp,
                const float* __restrict__ kern, float* __restrict__ out) {
    __shared__ short slabs[NSLAB * SLAB_SHORTS + 8];   // 18 KiB slabs + 16 B zeros
    const int t = threadIdx.x, wv = t >> 6, lane = t & 63;
    const int b = blockIdx.z, r = blockIdx.y;          // ho pair {2r, 2r+1}
    // block covers 16 wo x 2 ho; wave wv covers 4 same-parity columns per ho
    const int wo0 = (blockIdx.x << 4) + (wv & 1) + ((wv >> 1) << 3);
    const int wi0 = blockIdx.x << 3;                   // leftmost staged wi

    // cooperative slab staging WITH fused f32->bf16 convert: one slab = 512 f32
    // = 64 lanes x (2 float4 loads + pack8 + ds_write_b128). 18 slabs:
    // s in [0,9) -> input row r (hidx0, kh 1/2); s in [9,18) -> row r+1 (hidx1, kh0).
    const int hi0 = r;
    int hi1 = r + 1; if (hi1 > HiC - 1) hi1 = HiC - 1;
    #pragma unroll
    for (int k = 0; k < 5; ++k) {                      // s = wv, wv+4, ... (<=5)
        const int s = wv + 4 * k;
        if (s < NSLAB) {
            const int hi = (s >= 9) ? hi1 : hi0;
            int wi = wi0 + ((s >= 9) ? s - 9 : s); if (wi > WiC - 1) wi = WiC - 1;
            const float* g = img + (((b * HiC + hi) * WiC + wi) << 9) + lane * 8;
            float4 v0 = *(const float4*)g;
            float4 v1 = *(const float4*)(g + 4);
            *(short8*)&slabs[(s << 9) + lane * 8] = pack8(v0, v1);
        }
    }
    if (t < 8) slabs[NSLAB * SLAB_SHORTS + t] = 0;     // 16 B zero block
    __syncthreads();

    // even ho = 2r (CLS 0/1), then odd ho = 2r+1 (CLS 2/3), same slabs.
    if (wv & 1) {
        doCols<1>(slabs, bp, kern, out, b, 2 * r,     wo0, wi0, lane);
        doCols<3>(slabs, bp, kern, out, b, 2 * r + 1, wo0, wi0, lane);
    } else {
        doCols<0>(slabs, bp, kern, out, b, 2 * r,     wo0, wi0, lane);
        doCols<2>(slabs, bp, kern, out, b, 2 * r + 1, wo0, wi0, lane);
    }
}

extern "C" void kernel_launch(void* const* d_in, const int* in_sizes, int n_in,
                              void* d_out, int out_size, void* d_ws, size_t ws_size,
                              hipStream_t stream) {
    const float* images = (const float*)d_in[0];
    const int*   bp     = (const int*)d_in[1];
    const float* kern   = (const float*)d_in[2];
    float* out = (float*)d_out;
    (void)d_ws; (void)ws_size;   // ws untouched (poison fill is unconditional
                                 // anyway — round-2 lesson)

    dim3 grid(WoC / 16, HoC / 2, Bc), block(256);   // 8 x 64 x 2 = 1024 blocks
    hipLaunchKernelGGL(sconv_mfma, grid, block, 0, stream,
                       images, bp, kern, out);
}

// Round 5
// 93.864 us; speedup vs baseline: 1.0233x; 1.0233x over previous
//
#include <hip/hip_runtime.h>

// B=2, Hi=Wi=64, Di=32, C=16, F=8, strides (2,2,2), k=3x3x3, Ho=Wo=128, Do=64.
constexpr int Bc  = 2;
constexpr int HiC = 64, WiC = 64, DiC = 32;
constexpr int Cc  = 16, Fc  = 8;
constexpr int HoC = 128, WoC = 128, DoC = 64;

constexpr int SLAB_SHORTS = DiC * Cc;                  // 512 shorts = 1 KiB slab
constexpr int NSLAB       = 18;                        // 2 hi rows x 9 wi cols
constexpr int ZOFF        = NSLAB * SLAB_SHORTS * 2;   // LDS byte offset of zero block

typedef __attribute__((ext_vector_type(8))) short short8;   // 8 bf16 = A/B frag
typedef __attribute__((ext_vector_type(4))) float f32x4;    // MFMA accumulator

__device__ alignas(16) const float FZERO[8] = {0, 0, 0, 0, 0, 0, 0, 0};

__device__ __forceinline__ unsigned pk2(float x, float y) {   // RNE f32x2 -> bf16x2
    unsigned ux = __float_as_uint(x), uy = __float_as_uint(y);
    ux += ((ux >> 16) & 1u) + 0x7FFFu;
    uy += ((uy >> 16) & 1u) + 0x7FFFu;
    return (ux >> 16) | (uy & 0xFFFF0000u);
}
__device__ __forceinline__ short8 pack8(float4 a, float4 b) {
    union { unsigned u[4]; short8 s; } r;
    r.u[0] = pk2(a.x, a.y); r.u[1] = pk2(a.z, a.w);
    r.u[2] = pk2(b.x, b.y); r.u[3] = pk2(b.z, b.w);
    return r.s;
}

// Wave = 4 same-parity columns of one output row. Per column: out[do,f] over
// (pos,kd,c) packed in MFMA K=32. E rows (bp+do+1 even): per position, k-halves
// = kd0/kd2. O rows (kd=1): two positions per MFMA. A: A[m=lane&15][k=quad*8+j];
// B: B[k][n=lane&15]; C/D: col=lane&15, row=quad*4+reg. (round-7/8 verified)
// Round 13: round-3 structure restored (round-4 lesson: direct 64B-strided
// stores lose more to write sectoring than the LDS-transpose epilogue costs —
// keep fully-coalesced contiguous column stores). Change: __launch_bounds__
// (256,4) so all 4 blocks/CU are co-resident (grid 1024 = 4 x 256 CU; at
// (256,3) the 4th block serialized -> compute tail + less latency hiding).
template<int CLS>
__device__ __forceinline__ void doCols(const short* __restrict__ slabs,
                                       const int*   __restrict__ bp,
                                       const float* __restrict__ kern,
                                       float*       __restrict__ out,
                                       float*       __restrict__ ldsw,
                                       int b, int ho, int wo0, int wi0, int lane) {
    constexpr int NP = (CLS == 0) ? 1 : ((CLS == 3) ? 4 : 2);
    constexpr int OP = (NP + 1) / 2;
    constexpr int KH[4][4] = {{1,0,0,0},{1,1,0,0},{0,2,0,0},{0,0,2,2}};
    constexpr int KW[4][4] = {{1,0,0,0},{0,2,0,0},{1,1,0,0},{0,2,0,2}};

    const int quad = lane >> 4, n = lane & 15;
    const int half = quad >> 1, chalf = quad & 1;   // k-half, channel-half
    const int chalfB = chalf * 16;                  // byte offset within di row

    // ---- B fragments in-register from f32 kern (amortized over 4 columns) ----
    short8 bE[NP], bO[OP];
    #pragma unroll
    for (int p = 0; p < NP; ++p) {
        const int kp = KH[CLS][p] * 3 + KW[CLS][p];
        const float* wp = (n < Fc)
            ? kern + (kp * 3 + 2 * half) * 128 + n * 16 + chalf * 8 : FZERO;
        bE[p] = pack8(*(const float4*)wp, *(const float4*)(wp + 4));
    }
    #pragma unroll
    for (int pp = 0; pp < OP; ++pp) {
        const int  PA   = (2 * pp < NP) ? 2 * pp : 0;
        const bool hasB = (2 * pp + 1) < NP;
        const int  PB   = hasB ? (2 * pp + 1) : 0;
        const int kpa = KH[CLS][PA] * 3 + KW[CLS][PA];
        const int kpb = KH[CLS][PB] * 3 + KW[CLS][PB];
        const int kp  = half ? kpb : kpa;
        const bool v  = (n < Fc) && (!half || hasB);
        const float* wp = v ? kern + (kp * 3 + 1) * 128 + n * 16 + chalf * 8 : FZERO;
        bO[pp] = pack8(*(const float4*)wp, *(const float4*)(wp + 4));
    }

    // ---- phase 1: ALL scalar loads for all 4 columns ----
    int colx[4], bpcol[4], bpgr[4][NP], pxo[4][NP]; bool pvs[4][NP];
    #pragma unroll
    for (int cc = 0; cc < 4; ++cc) {
        const int wo = wo0 + 2 * cc;
        colx[cc]  = __builtin_amdgcn_readfirstlane((b * HoC + ho) * WoC + wo);
        bpcol[cc] = bp[colx[cc]];                    // uniform -> s_load
        #pragma unroll
        for (int p = 0; p < NP; ++p) {
            const int kh = KH[CLS][p], kw = KW[CLS][p];
            int hi = (ho + 1 - kh) >> 1; hi = hi > HiC - 1 ? HiC - 1 : hi;
            int wi = (wo + 1 - kw) >> 1; wi = wi > WiC - 1 ? WiC - 1 : wi;
            pvs[cc][p] = (kh != 0 || ho + 1 < HoC) && (kw != 0 || wo + 1 < WoC);
            const int sidx =
                __builtin_amdgcn_readfirstlane((b * HoC + 2 * hi) * WoC + 2 * wi);
            bpgr[cc][p] = bp[sidx];                  // uniform -> s_load
            const int hidx = (kh == 0) ? 1 : 0;      // row r+1 = kh0, row r = kh1/2
            pxo[cc][p] = __builtin_amdgcn_readfirstlane(
                             (hidx * 9 + (wi - wi0)) << 10);   // LDS bytes
        }
    }

    // ---- phase 2: per column taps + MFMA + epilogue ----
    #pragma unroll
    for (int cc = 0; cc < 4; ++cc) {
        const int bp_col = bpcol[cc];
        const int q      = (bp_col + 1) & 1;
        const int baseE  = (bp_col + q + 1) >> 1;    // di(kd0) = baseE+m-bpg
        const int baseO  = (bp_col + 1 - q) >> 1;    // di(kd1) = baseO+m-bpg
        int sE[NP], sO[NP];
        #pragma unroll
        for (int p = 0; p < NP; ++p) {               // sentinel folds validity
            const int bpg = bpgr[cc][p] >> 1;
            sE[p] = pvs[cc][p] ? baseE - bpg : -100000;
            sO[p] = pvs[cc][p] ? baseO - bpg : -100000;
        }

        f32x4 accE[2] = {{0.f,0.f,0.f,0.f},{0.f,0.f,0.f,0.f}};
        f32x4 accO[2] = {{0.f,0.f,0.f,0.f},{0.f,0.f,0.f,0.f}};

        #pragma unroll
        for (int g = 0; g < 2; ++g) {
            #pragma unroll
            for (int p = 0; p < NP; ++p) {           // E: kd = 2*half
                const int  di = sE[p] + 16 * g + n - half;
                const bool ok = (unsigned)di < (unsigned)DiC;
                const int  off = ok ? pxo[cc][p] + di * 32 + chalfB : ZOFF;
                short8 a = *(const short8*)((const char*)slabs + off);   // ds_read_b128
                accE[g] = __builtin_amdgcn_mfma_f32_16x16x32_bf16(a, bE[p], accE[g], 0, 0, 0);
            }
            #pragma unroll
            for (int pp = 0; pp < OP; ++pp) {        // O: k-halves = two positions
                const int  PA   = (2 * pp < NP) ? 2 * pp : 0;
                const bool hasB = (2 * pp + 1) < NP;
                const int  PB   = hasB ? (2 * pp + 1) : 0;
                const int  sOs  = half ? (hasB ? sO[PB] : -100000) : sO[PA];
                const int  pxs  = half ? pxo[cc][PB] : pxo[cc][PA];
                const int  di = sOs + 16 * g + n;
                const bool ok = (unsigned)di < (unsigned)DiC;
                const int  off = ok ? pxs + di * 32 + chalfB : ZOFF;
                short8 a = *(const short8*)((const char*)slabs + off);   // ds_read_b128
                accO[g] = __builtin_amdgcn_mfma_f32_16x16x32_bf16(a, bO[pp], accO[g], 0, 0, 0);
            }
        }

        // Wave-private LDS transpose: C/D (row=quad*4+r, col=n) -> [do][f] rows.
        __builtin_amdgcn_wave_barrier();
        if (n < Fc) {
            #pragma unroll
            for (int g = 0; g < 2; ++g) {
                #pragma unroll
                for (int r = 0; r < 4; ++r) {
                    const int m2 = 16 * g + quad * 4 + r;
                    ldsw[(2 * m2 + q) * Fc + n]     = accE[g][r];
                    ldsw[(2 * m2 + 1 - q) * Fc + n] = accO[g][r];
                }
            }
        }
        __builtin_amdgcn_wave_barrier();
        float* outc = out + (size_t)colx[cc] * (DoC * Fc);
        *(float4*)(outc + lane * 8)     = *(const float4*)(ldsw + lane * 8);
        *(float4*)(outc + lane * 8 + 4) = *(const float4*)(ldsw + lane * 8 + 4);
        __builtin_amdgcn_wave_barrier();
    }
}

__global__ __launch_bounds__(256, 4)
void sconv_mfma(const float* __restrict__ img, const int* __restrict__ bp,
                const float* __restrict__ kern, float* __restrict__ out) {
    __shared__ short slabs[NSLAB * SLAB_SHORTS + 8];   // 18 KiB slabs + 16 B zeros
    __shared__ float lds[4 * DoC * Fc];                // 8 KiB transpose scratch
    const int t = threadIdx.x, wv = t >> 6, lane = t & 63;
    const int b = blockIdx.z, r = blockIdx.y;          // ho pair {2r, 2r+1}
    // block covers 16 wo x 2 ho; wave wv covers 4 same-parity columns per ho
    const int wo0 = (blockIdx.x << 4) + (wv & 1) + ((wv >> 1) << 3);
    const int wi0 = blockIdx.x << 3;                   // leftmost staged wi
    float* ldsw = lds + wv * (DoC * Fc);

    // cooperative slab staging WITH fused f32->bf16 convert: one slab = 512 f32
    // = 64 lanes x (2 float4 loads + pack8 + ds_write_b128). 18 slabs:
    // s in [0,9) -> input row r (hidx0, kh 1/2); s in [9,18) -> row r+1 (hidx1, kh0).
    const int hi0 = r;
    int hi1 = r + 1; if (hi1 > HiC - 1) hi1 = HiC - 1;
    #pragma unroll
    for (int k = 0; k < 5; ++k) {                      // s = wv, wv+4, ... (<=5)
        const int s = wv + 4 * k;
        if (s < NSLAB) {
            const int hi = (s >= 9) ? hi1 : hi0;
            int wi = wi0 + ((s >= 9) ? s - 9 : s); if (wi > WiC - 1) wi = WiC - 1;
            const float* g = img + (((b * HiC + hi) * WiC + wi) << 9) + lane * 8;
            float4 v0 = *(const float4*)g;
            float4 v1 = *(const float4*)(g + 4);
            *(short8*)&slabs[(s << 9) + lane * 8] = pack8(v0, v1);
        }
    }
    if (t < 8) slabs[NSLAB * SLAB_SHORTS + t] = 0;     // 16 B zero block
    __syncthreads();

    // even ho = 2r (CLS 0/1), then odd ho = 2r+1 (CLS 2/3), same slabs.
    if (wv & 1) {
        doCols<1>(slabs, bp, kern, out, ldsw, b, 2 * r,     wo0, wi0, lane);
        doCols<3>(slabs, bp, kern, out, ldsw, b, 2 * r + 1, wo0, wi0, lane);
    } else {
        doCols<0>(slabs, bp, kern, out, ldsw, b, 2 * r,     wo0, wi0, lane);
        doCols<2>(slabs, bp, kern, out, ldsw, b, 2 * r + 1, wo0, wi0, lane);
    }
}

extern "C" void kernel_launch(void* const* d_in, const int* in_sizes, int n_in,
                              void* d_out, int out_size, void* d_ws, size_t ws_size,
                              hipStream_t stream) {
    const float* images = (const float*)d_in[0];
    const int*   bp     = (const int*)d_in[1];
    const float* kern   = (const float*)d_in[2];
    float* out = (float*)d_out;
    (void)d_ws; (void)ws_size;   // ws untouched (poison fill is unconditional
                                 // anyway — round-2 lesson)

    dim3 grid(WoC / 16, HoC / 2, Bc), block(256);   // 8 x 64 x 2 = 1024 blocks
    hipLaunchKernelGGL(sconv_mfma, grid, block, 0, stream,
                       images, bp, kern, out);
}